// Round 11
// baseline (586.706 us; speedup 1.0000x reference)
//
#include <hip/hip_runtime.h>
#include <hip/hip_bf16.h>
#include <math.h>

#define SCALE_ 0.17677669529663687f   // 32^-0.5

typedef __attribute__((ext_vector_type(8))) short s8v;
typedef __attribute__((ext_vector_type(4))) float f4v;

__device__ __forceinline__ unsigned short f2bf(float f) {
  unsigned int u = __float_as_uint(f);
  u += 0x7fffu + ((u >> 16) & 1u);
  return (unsigned short)(u >> 16);
}
__device__ __forceinline__ float bf2f(unsigned short h) {
  return __uint_as_float(((unsigned int)h) << 16);
}
__device__ __forceinline__ s8v cvt8(const float* __restrict__ p) {
  float4 a = *(const float4*)p;
  float4 b = *(const float4*)(p + 4);
  unsigned short o[8];
  o[0]=f2bf(a.x); o[1]=f2bf(a.y); o[2]=f2bf(a.z); o[3]=f2bf(a.w);
  o[4]=f2bf(b.x); o[5]=f2bf(b.y); o[6]=f2bf(b.z); o[7]=f2bf(b.w);
  return *(s8v*)o;
}
template<bool BW>
__device__ __forceinline__ s8v wload(const unsigned short* wb, const float* wf, size_t off) {
  if constexpr (BW) return *(const s8v*)(wb + off);
  else return cvt8(wf + off);
}

// ---------------------------------------------------------------- K0: weights f32 -> bf16 (once; only if ws has room)
__global__ __launch_bounds__(256) void k_wcvt(const float* __restrict__ qkvw,
    const float* __restrict__ projw, unsigned short* __restrict__ wb) {
  int id = blockIdx.x * 256 + threadIdx.x;   // 0..32767
  int i = id * 8;
  const float* src = (i < 196608) ? (qkvw + i) : (projw + (i - 196608));
  float4 a = *(const float4*)src;
  float4 b = *(const float4*)(src + 4);
  unsigned short o[8];
  o[0]=f2bf(a.x); o[1]=f2bf(a.y); o[2]=f2bf(a.z); o[3]=f2bf(a.w);
  o[4]=f2bf(b.x); o[5]=f2bf(b.y); o[6]=f2bf(b.z); o[7]=f2bf(b.w);
  *(float4*)(wb + i) = *(float4*)o;
}

// ---------------------------------------------------------------- K1: LayerNorm -> bf16, windowed (shifted) layout
__global__ __launch_bounds__(256) void k_ln(
    const float* __restrict__ x, const float* __restrict__ g,
    const float* __restrict__ b, unsigned short* __restrict__ xnw) {
  int lane = threadIdx.x & 63;
  int tok  = (blockIdx.x << 2) + (threadIdx.x >> 6);
  int bb = tok >> 14, y = (tok >> 7) & 127, xx = tok & 127;
  float4 v = *(const float4*)(x + ((size_t)tok << 8) + (lane << 2));
  float s  = v.x + v.y + v.z + v.w;
  float s2 = v.x*v.x + v.y*v.y + v.z*v.z + v.w*v.w;
#pragma unroll
  for (int o = 32; o >= 1; o >>= 1) { s += __shfl_xor(s, o); s2 += __shfl_xor(s2, o); }
  float mu  = s * (1.0f/256.0f);
  float var = s2 * (1.0f/256.0f) - mu*mu;
  float rs  = rsqrtf(fmaxf(var, 0.0f) + 1e-5f);
  float4 gv = ((const float4*)g)[lane];
  float4 bv = ((const float4*)b)[lane];
  unsigned short o[4];
  o[0] = f2bf((v.x - mu)*rs*gv.x + bv.x);
  o[1] = f2bf((v.y - mu)*rs*gv.y + bv.y);
  o[2] = f2bf((v.z - mu)*rs*gv.z + bv.z);
  o[3] = f2bf((v.w - mu)*rs*gv.w + bv.w);
  int sy = (y + 124) & 127, sx = (xx + 124) & 127;
  int win  = bb*256 + (sy >> 3)*16 + (sx >> 3);
  int wtok = (sy & 7)*8 + (sx & 7);
  *(uint2*)(xnw + (size_t)win*16384 + wtok*256 + (lane << 2)) = *(uint2*)o;
}

// ---------------------------------------------------------------- K2: depthwise 7x7 conv, register-tiled 4x4
__global__ __launch_bounds__(256) void k_dw(
    const unsigned short* __restrict__ xnw, const float* __restrict__ wgt,
    const float* __restrict__ dwbias, unsigned short* __restrict__ dw) {
  __shared__ float tile[22][22][17];
  int t = threadIdx.x;
  int x0 = blockIdx.x * 16, y0 = blockIdx.y * 16;
  int bb = blockIdx.z >> 4, cg = blockIdx.z & 15;
  int cl = t & 15;
  int c  = cg*16 + cl;
  for (int idx = t; idx < 1936; idx += 256) {
    int cq = idx & 3;
    int sp = idx >> 2;
    int xx = sp % 22, yy = sp / 22;
    int gy = y0 + yy - 3, gx = x0 + xx - 3;
    float4 v; v.x = v.y = v.z = v.w = 0.0f;
    if (gy >= 0 && gy < 128 && gx >= 0 && gx < 128) {
      int w2 = bb*256 + (gy >> 3)*16 + (gx >> 3);
      int t2 = (gy & 7)*8 + (gx & 7);
      uint2 u = *(const uint2*)(xnw + (size_t)w2*16384 + t2*256 + cg*16 + (cq << 2));
      v.x = bf2f((unsigned short)(u.x & 0xffff));
      v.y = bf2f((unsigned short)(u.x >> 16));
      v.z = bf2f((unsigned short)(u.y & 0xffff));
      v.w = bf2f((unsigned short)(u.y >> 16));
    }
    tile[yy][xx][cq*4+0] = v.x;
    tile[yy][xx][cq*4+1] = v.y;
    tile[yy][xx][cq*4+2] = v.z;
    tile[yy][xx][cq*4+3] = v.w;
  }
  float wr[49];
#pragma unroll
  for (int i = 0; i < 49; ++i) wr[i] = wgt[c*49 + i];
  float bdw = dwbias[c];
  __syncthreads();
  int qy = (t >> 4) & 3, qx = t >> 6;
  float acc[4][4];
#pragma unroll
  for (int i = 0; i < 4; ++i)
#pragma unroll
    for (int j = 0; j < 4; ++j) acc[i][j] = bdw;
#pragma unroll
  for (int ty = 0; ty < 10; ++ty) {
    float row[10];
#pragma unroll
    for (int j = 0; j < 10; ++j) row[j] = tile[qy*4 + ty][qx*4 + j][cl];
#pragma unroll
    for (int oy = 0; oy < 4; ++oy) {
      int ky = ty - oy;
      if (ky < 0 || ky > 6) continue;
#pragma unroll
      for (int ox = 0; ox < 4; ++ox)
#pragma unroll
        for (int kx = 0; kx < 7; ++kx)
          acc[oy][ox] += row[ox + kx] * wr[ky*7 + kx];
    }
  }
#pragma unroll
  for (int oy = 0; oy < 4; ++oy)
#pragma unroll
    for (int ox = 0; ox < 4; ++ox) {
      int gy = y0 + qy*4 + oy, gx = x0 + qx*4 + ox;
      int win = bb*256 + (gy >> 3)*16 + (gx >> 3);
      int tok = (gy & 7)*8 + (gx & 7);
      dw[(size_t)(win*64 + tok)*256 + c] = f2bf(acc[oy][ox]);
    }
}

// ---------------------------------------------------------------- K3: QKV GEMM, single-stage LDS, no inner barriers
// One 256-thr block per window; whole 64x256 A in LDS (16B-chunk XOR swizzle);
// two N-passes (wave covers 96 cols/pass). Q written IN PLACE over xn as [tok][256].
template<bool BW>
__global__ __launch_bounds__(256, 4) void k_qkvm(
    unsigned short* xnw, const unsigned short* wbq, const float* qkvw,
    const float* __restrict__ qkvb,
    unsigned short* __restrict__ Kb, unsigned short* __restrict__ Vt) {
  __shared__ unsigned short As[16384];   // [64][256] bf16, chunk-swizzled
  int t = threadIdx.x;
  int wv = t >> 6, lane = t & 63, g = lane >> 4, q = lane & 15;
  int win = blockIdx.x;
  unsigned short* xw = xnw + (size_t)win * 16384;

  { // stage full window: thread -> row t>>2, chunks (t&3)*8 .. +7 (16B each)
    int row = t >> 2, c0 = (t & 3) * 8;
    const unsigned short* src = xw + row*256 + c0*8;
#pragma unroll
    for (int j = 0; j < 8; ++j) {
      uint4 v = *(const uint4*)(src + j*8);
      *(uint4*)&As[row*256 + (((c0 + j) ^ (row & 7)) * 8)] = v;
    }
  }
  __syncthreads();   // all global xn reads complete; LDS holds the copy

  int xk = q & 7;
  for (int pass = 0; pass < 2; ++pass) {
    int cb = pass*384 + wv*96;
    f4v acc[4][6];
#pragma unroll
    for (int mi = 0; mi < 4; ++mi)
#pragma unroll
      for (int nj = 0; nj < 6; ++nj) acc[mi][nj] = f4v{0.f,0.f,0.f,0.f};
#pragma unroll 2
    for (int kc = 0; kc < 8; ++kc) {
      s8v af[4];
#pragma unroll
      for (int mi = 0; mi < 4; ++mi)
        af[mi] = *(const s8v*)&As[(mi*16 + q)*256 + (((kc*4 + g) ^ xk) * 8)];
      s8v bf[6];
#pragma unroll
      for (int nj = 0; nj < 6; ++nj)
        bf[nj] = wload<BW>(wbq, qkvw, (size_t)(cb + nj*16 + q)*256 + kc*32 + g*8);
#pragma unroll
      for (int mi = 0; mi < 4; ++mi)
#pragma unroll
        for (int nj = 0; nj < 6; ++nj)
          acc[mi][nj] = __builtin_amdgcn_mfma_f32_16x16x32_bf16(af[mi], bf[nj], acc[mi][nj], 0, 0, 0);
    }
    // epilogue for this pass's 96 cols
#pragma unroll
    for (int nj = 0; nj < 6; ++nj) {
      int col = cb + nj*16 + q;
      float bias = qkvb[col];
      int which = col >> 8;
      int h = (col >> 5) & 7, d = col & 31;
      if (which == 0) {          // Q in place, [win][tok][256] layout (ch = h*32+d)
        unsigned short* qdst = xw + h*32 + d;
#pragma unroll
        for (int mi = 0; mi < 4; ++mi)
#pragma unroll
          for (int r = 0; r < 4; ++r)
            qdst[(mi*16 + g*4 + r)*256] = f2bf((acc[mi][nj][r] + bias) * SCALE_);
      } else if (which == 1) {   // K [id][tok][32]
        unsigned short* kdst = Kb + ((size_t)(win*8 + h))*2048 + d;
#pragma unroll
        for (int mi = 0; mi < 4; ++mi)
#pragma unroll
          for (int r = 0; r < 4; ++r)
            kdst[(mi*16 + g*4 + r)*32] = f2bf(acc[mi][nj][r] + bias);
      } else {                   // V^T [id][d][tok]
        unsigned short* vdst = Vt + ((size_t)(win*8 + h))*2048 + d*64 + g*4;
#pragma unroll
        for (int mi = 0; mi < 4; ++mi) {
          uint2 pv;
          pv.x = (unsigned)f2bf(acc[mi][nj][0] + bias) | ((unsigned)f2bf(acc[mi][nj][1] + bias) << 16);
          pv.y = (unsigned)f2bf(acc[mi][nj][2] + bias) | ((unsigned)f2bf(acc[mi][nj][3] + bias) << 16);
          *(uint2*)(vdst + mi*16) = pv;
        }
      }
    }
  }
}

// ---------------------------------------------------------------- K4 (split path): attention, one wave per (win, head)
__global__ __launch_bounds__(64) void k_attn(
    const unsigned short* __restrict__ Qb, const unsigned short* __restrict__ Kb,
    const unsigned short* __restrict__ Vt, const float* __restrict__ rpb,
    unsigned short* __restrict__ yio) {
  __shared__ unsigned short pq[2560];   // [64][40]: P halves
  __shared__ float rpbs[225];
  int l = threadIdx.x, g = l >> 4, q = l & 15;
  int b = blockIdx.x;
  int win = (b >> 6)*8 + (b & 7);
  int h   = (b >> 3) & 7;
  int id  = win*8 + h;
  int wy15 = (((win >> 4) & 15) == 15), wx15 = ((win & 15) == 15);
  size_t base = (size_t)id << 11;
  for (int i = l; i < 225; i += 64) rpbs[i] = rpb[i*8 + h];

  f4v sM[4][4];
#pragma unroll
  for (int mi = 0; mi < 4; ++mi)
#pragma unroll
    for (int nj = 0; nj < 4; ++nj) sM[mi][nj] = f4v{0.f,0.f,0.f,0.f};
  {
    s8v qa[4], kb[4];
#pragma unroll
    for (int mi = 0; mi < 4; ++mi)
      qa[mi] = *(const s8v*)(Qb + (size_t)win*16384 + (mi*16 + q)*256 + h*32 + g*8);
#pragma unroll
    for (int nj = 0; nj < 4; ++nj) kb[nj] = *(const s8v*)(Kb + base + (nj*16 + q)*32 + g*8);
#pragma unroll
    for (int mi = 0; mi < 4; ++mi)
#pragma unroll
      for (int nj = 0; nj < 4; ++nj)
        sM[mi][nj] = __builtin_amdgcn_mfma_f32_16x16x32_bf16(qa[mi], kb[nj], sM[mi][nj], 0, 0, 0);
  }
  float rin[4][4];
#pragma unroll
  for (int mi = 0; mi < 4; ++mi)
#pragma unroll
    for (int r = 0; r < 4; ++r) {
      int i = mi*16 + g*4 + r;
      int iy = i >> 3, ix = i & 7;
      float sm = 0.f;
#pragma unroll
      for (int nj = 0; nj < 4; ++nj) {
        int j = nj*16 + q;
        int jy = j >> 3, jx = j & 7;
        int rel = (iy - jy + 7)*15 + (ix - jx + 7);
        int msk = (wy15 & (((iy ^ jy) >> 2) & 1)) | (wx15 & (((ix ^ jx) >> 2) & 1));
        float e = __expf(sM[mi][nj][r] + rpbs[rel] + (msk ? -100.0f : 0.0f));
        sM[mi][nj][r] = e;
        sm += e;
      }
      sm += __shfl_xor(sm, 1);
      sm += __shfl_xor(sm, 2);
      sm += __shfl_xor(sm, 4);
      sm += __shfl_xor(sm, 8);
      rin[mi][r] = 1.0f / sm;
    }
  f4v oc[4][2];
#pragma unroll
  for (int mi = 0; mi < 4; ++mi)
#pragma unroll
    for (int nv = 0; nv < 2; ++nv) oc[mi][nv] = f4v{0.f,0.f,0.f,0.f};
  for (int half = 0; half < 2; ++half) {
#pragma unroll
    for (int mi = 0; mi < 4; ++mi)
#pragma unroll
      for (int nl = 0; nl < 2; ++nl)
#pragma unroll
        for (int r = 0; r < 4; ++r) {
          int i = mi*16 + g*4 + r;
          pq[i*40 + nl*16 + q] = f2bf(sM[mi][half*2 + nl][r] * rin[mi][r]);
        }
    s8v pa[4], vb[2];
#pragma unroll
    for (int mi = 0; mi < 4; ++mi) pa[mi] = *(const s8v*)(pq + (mi*16 + q)*40 + g*8);
#pragma unroll
    for (int nv = 0; nv < 2; ++nv)
      vb[nv] = *(const s8v*)(Vt + base + (nv*16 + q)*64 + half*32 + g*8);
#pragma unroll
    for (int mi = 0; mi < 4; ++mi)
#pragma unroll
      for (int nv = 0; nv < 2; ++nv)
        oc[mi][nv] = __builtin_amdgcn_mfma_f32_16x16x32_bf16(pa[mi], vb[nv], oc[mi][nv], 0, 0, 0);
  }
#pragma unroll
  for (int mi = 0; mi < 4; ++mi)
#pragma unroll
    for (int nv = 0; nv < 2; ++nv)
#pragma unroll
      for (int r = 0; r < 4; ++r) {
        int tok = mi*16 + g*4 + r;
        int ch  = h*32 + nv*16 + q;
        size_t a = (size_t)(win*64 + tok)*256 + ch;
        yio[a] = f2bf(oc[mi][nv][r] + bf2f(yio[a]));
      }
}

// ---------------------------------------------------------------- K5 (split path): proj GEMM, LDS-staged A dbuf
template<bool BW>
__global__ __launch_bounds__(256) void k_proj(
    const unsigned short* __restrict__ yio, const unsigned short* wpb,
    const float* projw, const float* __restrict__ projb,
    const float* __restrict__ x, float* __restrict__ out) {
  __shared__ unsigned short As[2][4096];
  int t = threadIdx.x;
  int b = blockIdx.x;
  int ylo = b & 7, nx = (b >> 3) & 1, yhi = b >> 4;
  int y = yhi*8 + ylo;
  int wv = t >> 6, g = (t & 63) >> 4, q = t & 15;
  int rbase = (wv >> 1) * 64;
  int colg = nx*128 + (wv & 1)*64;

  int stok = t >> 1;
  int sg0  = (t & 1) << 1;
  int sperm = (stok >> 1) & 3;
  const unsigned short* src = yio + ((size_t)(y*128 + stok))*256 + sg0*8;
  int woff0 = stok*32 + ((sg0    ) ^ sperm)*8;
  int woff1 = stok*32 + ((sg0 + 1) ^ sperm)*8;
  int rperm = (g ^ ((q >> 1) & 3)) * 8;

  f4v acc[4][4];
#pragma unroll
  for (int mi = 0; mi < 4; ++mi)
#pragma unroll
    for (int nj = 0; nj < 4; ++nj) acc[mi][nj] = f4v{0.f,0.f,0.f,0.f};

  uint4 r0 = *(const uint4*)(src);
  uint4 r1 = *(const uint4*)(src + 8);
  *(uint4*)(&As[0][woff0]) = r0;
  *(uint4*)(&As[0][woff1]) = r1;
  __syncthreads();

  for (int kc = 0; kc < 8; ++kc) {
    int cur = kc & 1;
    if (kc < 7) {
      r0 = *(const uint4*)(src + (kc+1)*32);
      r1 = *(const uint4*)(src + (kc+1)*32 + 8);
    }
    s8v af[4], bf[4];
#pragma unroll
    for (int mi = 0; mi < 4; ++mi)
      af[mi] = *(const s8v*)(&As[cur][(rbase + mi*16 + q)*32 + rperm]);
#pragma unroll
    for (int nj = 0; nj < 4; ++nj)
      bf[nj] = wload<BW>(wpb, projw, (size_t)(colg + nj*16 + q)*256 + kc*32 + g*8);
#pragma unroll
    for (int mi = 0; mi < 4; ++mi)
#pragma unroll
      for (int nj = 0; nj < 4; ++nj)
        acc[mi][nj] = __builtin_amdgcn_mfma_f32_16x16x32_bf16(af[mi], bf[nj], acc[mi][nj], 0, 0, 0);
    if (kc < 7) {
      *(uint4*)(&As[cur ^ 1][woff0]) = r0;
      *(uint4*)(&As[cur ^ 1][woff1]) = r1;
      __syncthreads();
    }
  }

  float pb4[4];
#pragma unroll
  for (int nj = 0; nj < 4; ++nj) pb4[nj] = projb[colg + nj*16 + q];
#pragma unroll
  for (int mi = 0; mi < 4; ++mi)
#pragma unroll
    for (int r = 0; r < 4; ++r) {
      int row = y*128 + rbase + mi*16 + g*4 + r;
      int win = row >> 6, tok = row & 63;
      int bb = row >> 14;
      int sy = ((win >> 4) & 15)*8 + (tok >> 3);
      int sx = (win & 15)*8 + (tok & 7);
      int oy = (sy + 4) & 127, ox = (sx + 4) & 127;
      size_t rowb = ((size_t)((bb*128 + oy)*128 + ox)) << 8;
#pragma unroll
      for (int nj = 0; nj < 4; ++nj) {
        int ch = colg + nj*16 + q;
        out[rowb + ch] = x[rowb + ch] + acc[mi][nj][r] + pb4[nj];
      }
    }
}

// ---------------------------------------------------------------- K6 (fused path): attn + dw-add + proj + residual
// One 512-thr block per window; wave h = one head. A2 (LDS) = dw, += attn; proj GEMM -> out.
__global__ __launch_bounds__(512, 4) void k_attnproj(
    const unsigned short* __restrict__ Qb, const unsigned short* __restrict__ Kb,
    const unsigned short* __restrict__ Vt, const unsigned short* __restrict__ dwy,
    const unsigned short* __restrict__ wbp, const float* __restrict__ projb,
    const float* __restrict__ rpb, const float* __restrict__ x,
    float* __restrict__ out) {
  __shared__ unsigned short A2[16640];      // [64][260] bf16
  __shared__ unsigned short pp[8][2560];    // per-wave [64][40] P buf
  __shared__ float rpbs[1800];
  int t = threadIdx.x;
  int h = t >> 6, l = t & 63, g = l >> 4, q = l & 15;
  int win = blockIdx.x;
  int bb = win >> 8, wy = (win >> 4) & 15, wx = win & 15;
  int wy15 = (wy == 15), wx15 = (wx == 15);
  size_t base = ((size_t)(win*8 + h)) << 11;
  unsigned short* ph = pp[h];

  // phase 0: stage rpb (f32) + dw -> A2
  for (int i = t; i < 1800; i += 512) rpbs[i] = rpb[i];
  for (int i = t; i < 2048; i += 512) {
    int row = i >> 5, col = (i & 31) << 3;
    *(uint4*)&A2[row*260 + col] = *(const uint4*)(dwy + (size_t)win*16384 + i*8);
  }
  __syncthreads();

  // phase 1: attention, head h
  f4v sM[4][4];
#pragma unroll
  for (int mi = 0; mi < 4; ++mi)
#pragma unroll
    for (int nj = 0; nj < 4; ++nj) sM[mi][nj] = f4v{0.f,0.f,0.f,0.f};
  {
    s8v qa[4], kb[4];
#pragma unroll
    for (int mi = 0; mi < 4; ++mi)
      qa[mi] = *(const s8v*)(Qb + (size_t)win*16384 + (mi*16 + q)*256 + h*32 + g*8);
#pragma unroll
    for (int nj = 0; nj < 4; ++nj) kb[nj] = *(const s8v*)(Kb + base + (nj*16 + q)*32 + g*8);
#pragma unroll
    for (int mi = 0; mi < 4; ++mi)
#pragma unroll
      for (int nj = 0; nj < 4; ++nj)
        sM[mi][nj] = __builtin_amdgcn_mfma_f32_16x16x32_bf16(qa[mi], kb[nj], sM[mi][nj], 0, 0, 0);
  }
  float rin[4][4];
#pragma unroll
  for (int mi = 0; mi < 4; ++mi)
#pragma unroll
    for (int r = 0; r < 4; ++r) {
      int i = mi*16 + g*4 + r;
      int iy = i >> 3, ix = i & 7;
      float sm = 0.f;
#pragma unroll
      for (int nj = 0; nj < 4; ++nj) {
        int j = nj*16 + q;
        int jy = j >> 3, jx = j & 7;
        int rel = (iy - jy + 7)*15 + (ix - jx + 7);
        int msk = (wy15 & (((iy ^ jy) >> 2) & 1)) | (wx15 & (((ix ^ jx) >> 2) & 1));
        float e = __expf(sM[mi][nj][r] + rpbs[rel*8 + h] + (msk ? -100.0f : 0.0f));
        sM[mi][nj][r] = e;
        sm += e;
      }
      sm += __shfl_xor(sm, 1);
      sm += __shfl_xor(sm, 2);
      sm += __shfl_xor(sm, 4);
      sm += __shfl_xor(sm, 8);
      rin[mi][r] = 1.0f / sm;
    }
  f4v oc[4][2];
#pragma unroll
  for (int mi = 0; mi < 4; ++mi)
#pragma unroll
    for (int nv = 0; nv < 2; ++nv) oc[mi][nv] = f4v{0.f,0.f,0.f,0.f};
  for (int half = 0; half < 2; ++half) {
#pragma unroll
    for (int mi = 0; mi < 4; ++mi)
#pragma unroll
      for (int nl = 0; nl < 2; ++nl)
#pragma unroll
        for (int r = 0; r < 4; ++r) {
          int i = mi*16 + g*4 + r;
          ph[i*40 + nl*16 + q] = f2bf(sM[mi][half*2 + nl][r] * rin[mi][r]);
        }
    s8v pa[4], vb[2];
#pragma unroll
    for (int mi = 0; mi < 4; ++mi) pa[mi] = *(const s8v*)(ph + (mi*16 + q)*40 + g*8);
#pragma unroll
    for (int nv = 0; nv < 2; ++nv)
      vb[nv] = *(const s8v*)(Vt + base + (nv*16 + q)*64 + half*32 + g*8);
#pragma unroll
    for (int mi = 0; mi < 4; ++mi)
#pragma unroll
      for (int nv = 0; nv < 2; ++nv)
        oc[mi][nv] = __builtin_amdgcn_mfma_f32_16x16x32_bf16(pa[mi], vb[nv], oc[mi][nv], 0, 0, 0);
  }
  // A2 += attn (wave owns cols h*32..h*32+31; rows all)
#pragma unroll
  for (int mi = 0; mi < 4; ++mi)
#pragma unroll
    for (int nv = 0; nv < 2; ++nv)
#pragma unroll
      for (int r = 0; r < 4; ++r) {
        int tok = mi*16 + g*4 + r;
        int idx = tok*260 + h*32 + nv*16 + q;
        A2[idx] = f2bf(oc[mi][nv][r] + bf2f(A2[idx]));
      }
  __syncthreads();

  // phase 2: proj GEMM, wave h -> output cols h*32..+31
  f4v acc[4][2];
#pragma unroll
  for (int mi = 0; mi < 4; ++mi)
#pragma unroll
    for (int nv = 0; nv < 2; ++nv) acc[mi][nv] = f4v{0.f,0.f,0.f,0.f};
#pragma unroll 2
  for (int kc = 0; kc < 8; ++kc) {
    s8v af[4];
#pragma unroll
    for (int mi = 0; mi < 4; ++mi)
      af[mi] = *(const s8v*)&A2[(mi*16 + q)*260 + kc*32 + g*8];
    s8v bf2v[2];
#pragma unroll
    for (int nv = 0; nv < 2; ++nv)
      bf2v[nv] = *(const s8v*)(wbp + (size_t)(h*32 + nv*16 + q)*256 + kc*32 + g*8);
#pragma unroll
    for (int mi = 0; mi < 4; ++mi)
#pragma unroll
      for (int nv = 0; nv < 2; ++nv)
        acc[mi][nv] = __builtin_amdgcn_mfma_f32_16x16x32_bf16(af[mi], bf2v[nv], acc[mi][nv], 0, 0, 0);
  }
  float pb2[2];
  pb2[0] = projb[h*32 + q];
  pb2[1] = projb[h*32 + 16 + q];
#pragma unroll
  for (int mi = 0; mi < 4; ++mi)
#pragma unroll
    for (int r = 0; r < 4; ++r) {
      int tok = mi*16 + g*4 + r;
      int sy = wy*8 + (tok >> 3), sx = wx*8 + (tok & 7);
      int oy = (sy + 4) & 127, ox = (sx + 4) & 127;
      size_t rowb = ((size_t)((bb*128 + oy)*128 + ox)) << 8;
#pragma unroll
      for (int nv = 0; nv < 2; ++nv) {
        int ch = h*32 + nv*16 + q;
        out[rowb + ch] = x[rowb + ch] + acc[mi][nv][r] + pb2[nv];
      }
    }
}

extern "C" void kernel_launch(void* const* d_in, const int* in_sizes, int n_in,
                              void* d_out, int out_size, void* d_ws, size_t ws_size,
                              hipStream_t stream) {
  (void)in_sizes; (void)n_in; (void)out_size;
  const float* x     = (const float*)d_in[0];
  // d_in[1] = mask (analytic), d_in[2] = x_size (hardcoded 128)
  const float* g     = (const float*)d_in[3];
  const float* bln   = (const float*)d_in[4];
  const float* dww   = (const float*)d_in[5];
  const float* dwb_  = (const float*)d_in[6];
  const float* qkvw  = (const float*)d_in[7];
  const float* qkvb  = (const float*)d_in[8];
  const float* projw = (const float*)d_in[9];
  const float* projb = (const float*)d_in[10];
  const float* rpb   = (const float*)d_in[11];

  unsigned short* wsu = (unsigned short*)d_ws;
  unsigned short* xnw = wsu;                  // 64 MiB: xn -> Q in place
  unsigned short* dwy = wsu + 33554432;       // 64 MiB: dw (-> yio in split path)
  bool fused = ws_size >= 268959744ull;       // 256.5 MiB
  bool bw    = fused || ws_size >= 134742016ull;  // 128.5 MiB
  unsigned short *Kb, *Vt, *wb;
  if (fused) {
    Kb = wsu + 67108864;                      // ws + 128 MiB
    Vt = wsu + 100663296;                     // ws + 192 MiB
    wb = wsu + 134217728;                     // ws + 256 MiB
  } else {
    Kb = (unsigned short*)d_out;              // d_out doubles as K|Vt until k_proj
    Vt = Kb + 33554432;
    wb = wsu + 67108864;                      // ws + 128 MiB
  }
  float* outp = (float*)d_out;

  if (bw) k_wcvt<<<dim3(128), dim3(256), 0, stream>>>(qkvw, projw, wb);
  k_ln<<<dim3(32768),     dim3(256), 0, stream>>>(x, g, bln, xnw);
  k_dw<<<dim3(8, 8, 128), dim3(256), 0, stream>>>(xnw, dww, dwb_, dwy);
  if (bw) k_qkvm<true ><<<dim3(2048), dim3(256), 0, stream>>>(xnw, wb, qkvw, qkvb, Kb, Vt);
  else    k_qkvm<false><<<dim3(2048), dim3(256), 0, stream>>>(xnw, wb, qkvw, qkvb, Kb, Vt);

  if (fused) {
    k_attnproj<<<dim3(2048), dim3(512), 0, stream>>>(xnw, Kb, Vt, dwy, wb + 196608,
                                                     projb, rpb, x, outp);
  } else {
    k_attn<<<dim3(16384), dim3(64), 0, stream>>>(xnw, Kb, Vt, rpb, dwy);
    if (bw) k_proj<true ><<<dim3(2048), dim3(256), 0, stream>>>(dwy, wb + 196608, projw, projb, x, outp);
    else    k_proj<false><<<dim3(2048), dim3(256), 0, stream>>>(dwy, wb + 196608, projw, projb, x, outp);
  }
}

// Round 12
// 411.636 us; speedup vs baseline: 1.4253x; 1.4253x over previous
//
#include <hip/hip_runtime.h>
#include <hip/hip_bf16.h>
#include <math.h>

#define SCALE_ 0.17677669529663687f   // 32^-0.5

typedef __attribute__((ext_vector_type(8))) short s8v;
typedef __attribute__((ext_vector_type(4))) float f4v;

__device__ __forceinline__ unsigned short f2bf(float f) {
  unsigned int u = __float_as_uint(f);
  u += 0x7fffu + ((u >> 16) & 1u);
  return (unsigned short)(u >> 16);
}
__device__ __forceinline__ float bf2f(unsigned short h) {
  return __uint_as_float(((unsigned int)h) << 16);
}
__device__ __forceinline__ s8v cvt8(const float* __restrict__ p) {
  float4 a = *(const float4*)p;
  float4 b = *(const float4*)(p + 4);
  unsigned short o[8];
  o[0]=f2bf(a.x); o[1]=f2bf(a.y); o[2]=f2bf(a.z); o[3]=f2bf(a.w);
  o[4]=f2bf(b.x); o[5]=f2bf(b.y); o[6]=f2bf(b.z); o[7]=f2bf(b.w);
  return *(s8v*)o;
}
template<bool BW>
__device__ __forceinline__ s8v wload(const unsigned short* wb, const float* wf, size_t off) {
  if constexpr (BW) return *(const s8v*)(wb + off);
  else return cvt8(wf + off);
}

// ---------------------------------------------------------------- K0: weights f32 -> bf16 (once; only if ws has room)
__global__ __launch_bounds__(256) void k_wcvt(const float* __restrict__ qkvw,
    const float* __restrict__ projw, unsigned short* __restrict__ wb) {
  int id = blockIdx.x * 256 + threadIdx.x;   // 0..32767
  int i = id * 8;
  const float* src = (i < 196608) ? (qkvw + i) : (projw + (i - 196608));
  float4 a = *(const float4*)src;
  float4 b = *(const float4*)(src + 4);
  unsigned short o[8];
  o[0]=f2bf(a.x); o[1]=f2bf(a.y); o[2]=f2bf(a.z); o[3]=f2bf(a.w);
  o[4]=f2bf(b.x); o[5]=f2bf(b.y); o[6]=f2bf(b.z); o[7]=f2bf(b.w);
  *(float4*)(wb + i) = *(float4*)o;
}

// ---------------------------------------------------------------- K1: LayerNorm -> bf16, windowed (shifted) layout
__global__ __launch_bounds__(256) void k_ln(
    const float* __restrict__ x, const float* __restrict__ g,
    const float* __restrict__ b, unsigned short* __restrict__ xnw) {
  int lane = threadIdx.x & 63;
  int tok  = (blockIdx.x << 2) + (threadIdx.x >> 6);
  int bb = tok >> 14, y = (tok >> 7) & 127, xx = tok & 127;
  float4 v = *(const float4*)(x + ((size_t)tok << 8) + (lane << 2));
  float s  = v.x + v.y + v.z + v.w;
  float s2 = v.x*v.x + v.y*v.y + v.z*v.z + v.w*v.w;
#pragma unroll
  for (int o = 32; o >= 1; o >>= 1) { s += __shfl_xor(s, o); s2 += __shfl_xor(s2, o); }
  float mu  = s * (1.0f/256.0f);
  float var = s2 * (1.0f/256.0f) - mu*mu;
  float rs  = rsqrtf(fmaxf(var, 0.0f) + 1e-5f);
  float4 gv = ((const float4*)g)[lane];
  float4 bv = ((const float4*)b)[lane];
  unsigned short o[4];
  o[0] = f2bf((v.x - mu)*rs*gv.x + bv.x);
  o[1] = f2bf((v.y - mu)*rs*gv.y + bv.y);
  o[2] = f2bf((v.z - mu)*rs*gv.z + bv.z);
  o[3] = f2bf((v.w - mu)*rs*gv.w + bv.w);
  int sy = (y + 124) & 127, sx = (xx + 124) & 127;
  int win  = bb*256 + (sy >> 3)*16 + (sx >> 3);
  int wtok = (sy & 7)*8 + (sx & 7);
  *(uint2*)(xnw + (size_t)win*16384 + wtok*256 + (lane << 2)) = *(uint2*)o;
}

// ---------------------------------------------------------------- K2: depthwise 7x7 conv, register-tiled 4x4
__global__ __launch_bounds__(256) void k_dw(
    const unsigned short* __restrict__ xnw, const float* __restrict__ wgt,
    const float* __restrict__ dwbias, unsigned short* __restrict__ dw) {
  __shared__ float tile[22][22][17];
  int t = threadIdx.x;
  int x0 = blockIdx.x * 16, y0 = blockIdx.y * 16;
  int bb = blockIdx.z >> 4, cg = blockIdx.z & 15;
  int cl = t & 15;
  int c  = cg*16 + cl;
  for (int idx = t; idx < 1936; idx += 256) {
    int cq = idx & 3;
    int sp = idx >> 2;
    int xx = sp % 22, yy = sp / 22;
    int gy = y0 + yy - 3, gx = x0 + xx - 3;
    float4 v; v.x = v.y = v.z = v.w = 0.0f;
    if (gy >= 0 && gy < 128 && gx >= 0 && gx < 128) {
      int w2 = bb*256 + (gy >> 3)*16 + (gx >> 3);
      int t2 = (gy & 7)*8 + (gx & 7);
      uint2 u = *(const uint2*)(xnw + (size_t)w2*16384 + t2*256 + cg*16 + (cq << 2));
      v.x = bf2f((unsigned short)(u.x & 0xffff));
      v.y = bf2f((unsigned short)(u.x >> 16));
      v.z = bf2f((unsigned short)(u.y & 0xffff));
      v.w = bf2f((unsigned short)(u.y >> 16));
    }
    tile[yy][xx][cq*4+0] = v.x;
    tile[yy][xx][cq*4+1] = v.y;
    tile[yy][xx][cq*4+2] = v.z;
    tile[yy][xx][cq*4+3] = v.w;
  }
  float wr[49];
#pragma unroll
  for (int i = 0; i < 49; ++i) wr[i] = wgt[c*49 + i];
  float bdw = dwbias[c];
  __syncthreads();
  int qy = (t >> 4) & 3, qx = t >> 6;
  float acc[4][4];
#pragma unroll
  for (int i = 0; i < 4; ++i)
#pragma unroll
    for (int j = 0; j < 4; ++j) acc[i][j] = bdw;
#pragma unroll
  for (int ty = 0; ty < 10; ++ty) {
    float row[10];
#pragma unroll
    for (int j = 0; j < 10; ++j) row[j] = tile[qy*4 + ty][qx*4 + j][cl];
#pragma unroll
    for (int oy = 0; oy < 4; ++oy) {
      int ky = ty - oy;
      if (ky < 0 || ky > 6) continue;
#pragma unroll
      for (int ox = 0; ox < 4; ++ox)
#pragma unroll
        for (int kx = 0; kx < 7; ++kx)
          acc[oy][ox] += row[ox + kx] * wr[ky*7 + kx];
    }
  }
#pragma unroll
  for (int oy = 0; oy < 4; ++oy)
#pragma unroll
    for (int ox = 0; ox < 4; ++ox) {
      int gy = y0 + qy*4 + oy, gx = x0 + qx*4 + ox;
      int win = bb*256 + (gy >> 3)*16 + (gx >> 3);
      int tok = (gy & 7)*8 + (gx & 7);
      dw[(size_t)(win*64 + tok)*256 + c] = f2bf(acc[oy][ox]);
    }
}

// ---------------------------------------------------------------- K3: QKV GEMM, single-stage LDS, no inner barriers
// 256 thr/window; whole 64x256 A in LDS (16B-chunk XOR swizzle); THREE N-passes,
// wave covers 64 cols/pass (acc[4][4] = 64 VGPR, fits without spill).
// pass 0 = Q (in place over xn, [tok][256]), pass 1 = K, pass 2 = V^T.
template<bool BW>
__global__ __launch_bounds__(256) void k_qkvm(
    unsigned short* xnw, const unsigned short* wbq, const float* qkvw,
    const float* __restrict__ qkvb,
    unsigned short* __restrict__ Kb, unsigned short* __restrict__ Vt) {
  __shared__ unsigned short As[16384];   // [64][256] bf16, chunk-swizzled
  int t = threadIdx.x;
  int wv = t >> 6, lane = t & 63, g = lane >> 4, q = lane & 15;
  int win = blockIdx.x;
  unsigned short* xw = xnw + (size_t)win * 16384;

  { // stage full window: thread -> row t>>2, chunks (t&3)*8 .. +7 (16B each)
    int row = t >> 2, c0 = (t & 3) * 8;
    const unsigned short* src = xw + row*256 + c0*8;
#pragma unroll
    for (int j = 0; j < 8; ++j) {
      uint4 v = *(const uint4*)(src + j*8);
      *(uint4*)&As[row*256 + (((c0 + j) ^ (row & 7)) * 8)] = v;
    }
  }
  __syncthreads();   // all global xn reads complete; LDS holds the copy

  int xk = q & 7;
  for (int pass = 0; pass < 3; ++pass) {
    int cb = pass*256 + wv*64;
    f4v acc[4][4];
#pragma unroll
    for (int mi = 0; mi < 4; ++mi)
#pragma unroll
      for (int nj = 0; nj < 4; ++nj) acc[mi][nj] = f4v{0.f,0.f,0.f,0.f};
#pragma unroll 2
    for (int kc = 0; kc < 8; ++kc) {
      s8v af[4];
#pragma unroll
      for (int mi = 0; mi < 4; ++mi)
        af[mi] = *(const s8v*)&As[(mi*16 + q)*256 + (((kc*4 + g) ^ xk) * 8)];
      s8v bf[4];
#pragma unroll
      for (int nj = 0; nj < 4; ++nj)
        bf[nj] = wload<BW>(wbq, qkvw, (size_t)(cb + nj*16 + q)*256 + kc*32 + g*8);
#pragma unroll
      for (int mi = 0; mi < 4; ++mi)
#pragma unroll
        for (int nj = 0; nj < 4; ++nj)
          acc[mi][nj] = __builtin_amdgcn_mfma_f32_16x16x32_bf16(af[mi], bf[nj], acc[mi][nj], 0, 0, 0);
    }
    // epilogue for this pass's 64 cols (pass == which)
#pragma unroll
    for (int nj = 0; nj < 4; ++nj) {
      int col = cb + nj*16 + q;          // 0..767
      float bias = qkvb[col];
      int h = (col >> 5) & 7, d = col & 31;
      if (pass == 0) {           // Q in place, [win][tok][256] (ch = h*32+d), pre-scaled
        unsigned short* qdst = xw + h*32 + d;
#pragma unroll
        for (int mi = 0; mi < 4; ++mi)
#pragma unroll
          for (int r = 0; r < 4; ++r)
            qdst[(mi*16 + g*4 + r)*256] = f2bf((acc[mi][nj][r] + bias) * SCALE_);
      } else if (pass == 1) {    // K [id][tok][32]
        unsigned short* kdst = Kb + ((size_t)(win*8 + h))*2048 + d;
#pragma unroll
        for (int mi = 0; mi < 4; ++mi)
#pragma unroll
          for (int r = 0; r < 4; ++r)
            kdst[(mi*16 + g*4 + r)*32] = f2bf(acc[mi][nj][r] + bias);
      } else {                   // V^T [id][d][tok], packed 8B over r
        unsigned short* vdst = Vt + ((size_t)(win*8 + h))*2048 + d*64 + g*4;
#pragma unroll
        for (int mi = 0; mi < 4; ++mi) {
          uint2 pv;
          pv.x = (unsigned)f2bf(acc[mi][nj][0] + bias) | ((unsigned)f2bf(acc[mi][nj][1] + bias) << 16);
          pv.y = (unsigned)f2bf(acc[mi][nj][2] + bias) | ((unsigned)f2bf(acc[mi][nj][3] + bias) << 16);
          *(uint2*)(vdst + mi*16) = pv;
        }
      }
    }
  }
}

// ---------------------------------------------------------------- K4 (split path): attention, one wave per (win, head)
__global__ __launch_bounds__(64) void k_attn(
    const unsigned short* __restrict__ Qb, const unsigned short* __restrict__ Kb,
    const unsigned short* __restrict__ Vt, const float* __restrict__ rpb,
    unsigned short* __restrict__ yio) {
  __shared__ unsigned short pq[2560];   // [64][40]: P halves
  __shared__ float rpbs[225];
  int l = threadIdx.x, g = l >> 4, q = l & 15;
  int b = blockIdx.x;
  int win = (b >> 6)*8 + (b & 7);
  int h   = (b >> 3) & 7;
  int id  = win*8 + h;
  int wy15 = (((win >> 4) & 15) == 15), wx15 = ((win & 15) == 15);
  size_t base = (size_t)id << 11;
  for (int i = l; i < 225; i += 64) rpbs[i] = rpb[i*8 + h];

  f4v sM[4][4];
#pragma unroll
  for (int mi = 0; mi < 4; ++mi)
#pragma unroll
    for (int nj = 0; nj < 4; ++nj) sM[mi][nj] = f4v{0.f,0.f,0.f,0.f};
  {
    s8v qa[4], kb[4];
#pragma unroll
    for (int mi = 0; mi < 4; ++mi)
      qa[mi] = *(const s8v*)(Qb + (size_t)win*16384 + (mi*16 + q)*256 + h*32 + g*8);
#pragma unroll
    for (int nj = 0; nj < 4; ++nj) kb[nj] = *(const s8v*)(Kb + base + (nj*16 + q)*32 + g*8);
#pragma unroll
    for (int mi = 0; mi < 4; ++mi)
#pragma unroll
      for (int nj = 0; nj < 4; ++nj)
        sM[mi][nj] = __builtin_amdgcn_mfma_f32_16x16x32_bf16(qa[mi], kb[nj], sM[mi][nj], 0, 0, 0);
  }
  float rin[4][4];
#pragma unroll
  for (int mi = 0; mi < 4; ++mi)
#pragma unroll
    for (int r = 0; r < 4; ++r) {
      int i = mi*16 + g*4 + r;
      int iy = i >> 3, ix = i & 7;
      float sm = 0.f;
#pragma unroll
      for (int nj = 0; nj < 4; ++nj) {
        int j = nj*16 + q;
        int jy = j >> 3, jx = j & 7;
        int rel = (iy - jy + 7)*15 + (ix - jx + 7);
        int msk = (wy15 & (((iy ^ jy) >> 2) & 1)) | (wx15 & (((ix ^ jx) >> 2) & 1));
        float e = __expf(sM[mi][nj][r] + rpbs[rel] + (msk ? -100.0f : 0.0f));
        sM[mi][nj][r] = e;
        sm += e;
      }
      sm += __shfl_xor(sm, 1);
      sm += __shfl_xor(sm, 2);
      sm += __shfl_xor(sm, 4);
      sm += __shfl_xor(sm, 8);
      rin[mi][r] = 1.0f / sm;
    }
  f4v oc[4][2];
#pragma unroll
  for (int mi = 0; mi < 4; ++mi)
#pragma unroll
    for (int nv = 0; nv < 2; ++nv) oc[mi][nv] = f4v{0.f,0.f,0.f,0.f};
  for (int half = 0; half < 2; ++half) {
#pragma unroll
    for (int mi = 0; mi < 4; ++mi)
#pragma unroll
      for (int nl = 0; nl < 2; ++nl)
#pragma unroll
        for (int r = 0; r < 4; ++r) {
          int i = mi*16 + g*4 + r;
          pq[i*40 + nl*16 + q] = f2bf(sM[mi][half*2 + nl][r] * rin[mi][r]);
        }
    s8v pa[4], vb[2];
#pragma unroll
    for (int mi = 0; mi < 4; ++mi) pa[mi] = *(const s8v*)(pq + (mi*16 + q)*40 + g*8);
#pragma unroll
    for (int nv = 0; nv < 2; ++nv)
      vb[nv] = *(const s8v*)(Vt + base + (nv*16 + q)*64 + half*32 + g*8);
#pragma unroll
    for (int mi = 0; mi < 4; ++mi)
#pragma unroll
      for (int nv = 0; nv < 2; ++nv)
        oc[mi][nv] = __builtin_amdgcn_mfma_f32_16x16x32_bf16(pa[mi], vb[nv], oc[mi][nv], 0, 0, 0);
  }
#pragma unroll
  for (int mi = 0; mi < 4; ++mi)
#pragma unroll
    for (int nv = 0; nv < 2; ++nv)
#pragma unroll
      for (int r = 0; r < 4; ++r) {
        int tok = mi*16 + g*4 + r;
        int ch  = h*32 + nv*16 + q;
        size_t a = (size_t)(win*64 + tok)*256 + ch;
        yio[a] = f2bf(oc[mi][nv][r] + bf2f(yio[a]));
      }
}

// ---------------------------------------------------------------- K5 (split path): proj GEMM, LDS-staged A dbuf
template<bool BW>
__global__ __launch_bounds__(256) void k_proj(
    const unsigned short* __restrict__ yio, const unsigned short* wpb,
    const float* projw, const float* __restrict__ projb,
    const float* __restrict__ x, float* __restrict__ out) {
  __shared__ unsigned short As[2][4096];
  int t = threadIdx.x;
  int b = blockIdx.x;
  int ylo = b & 7, nx = (b >> 3) & 1, yhi = b >> 4;
  int y = yhi*8 + ylo;
  int wv = t >> 6, g = (t & 63) >> 4, q = t & 15;
  int rbase = (wv >> 1) * 64;
  int colg = nx*128 + (wv & 1)*64;

  int stok = t >> 1;
  int sg0  = (t & 1) << 1;
  int sperm = (stok >> 1) & 3;
  const unsigned short* src = yio + ((size_t)(y*128 + stok))*256 + sg0*8;
  int woff0 = stok*32 + ((sg0    ) ^ sperm)*8;
  int woff1 = stok*32 + ((sg0 + 1) ^ sperm)*8;
  int rperm = (g ^ ((q >> 1) & 3)) * 8;

  f4v acc[4][4];
#pragma unroll
  for (int mi = 0; mi < 4; ++mi)
#pragma unroll
    for (int nj = 0; nj < 4; ++nj) acc[mi][nj] = f4v{0.f,0.f,0.f,0.f};

  uint4 r0 = *(const uint4*)(src);
  uint4 r1 = *(const uint4*)(src + 8);
  *(uint4*)(&As[0][woff0]) = r0;
  *(uint4*)(&As[0][woff1]) = r1;
  __syncthreads();

  for (int kc = 0; kc < 8; ++kc) {
    int cur = kc & 1;
    if (kc < 7) {
      r0 = *(const uint4*)(src + (kc+1)*32);
      r1 = *(const uint4*)(src + (kc+1)*32 + 8);
    }
    s8v af[4], bf[4];
#pragma unroll
    for (int mi = 0; mi < 4; ++mi)
      af[mi] = *(const s8v*)(&As[cur][(rbase + mi*16 + q)*32 + rperm]);
#pragma unroll
    for (int nj = 0; nj < 4; ++nj)
      bf[nj] = wload<BW>(wpb, projw, (size_t)(colg + nj*16 + q)*256 + kc*32 + g*8);
#pragma unroll
    for (int mi = 0; mi < 4; ++mi)
#pragma unroll
      for (int nj = 0; nj < 4; ++nj)
        acc[mi][nj] = __builtin_amdgcn_mfma_f32_16x16x32_bf16(af[mi], bf[nj], acc[mi][nj], 0, 0, 0);
    if (kc < 7) {
      *(uint4*)(&As[cur ^ 1][woff0]) = r0;
      *(uint4*)(&As[cur ^ 1][woff1]) = r1;
      __syncthreads();
    }
  }

  float pb4[4];
#pragma unroll
  for (int nj = 0; nj < 4; ++nj) pb4[nj] = projb[colg + nj*16 + q];
#pragma unroll
  for (int mi = 0; mi < 4; ++mi)
#pragma unroll
    for (int r = 0; r < 4; ++r) {
      int row = y*128 + rbase + mi*16 + g*4 + r;
      int win = row >> 6, tok = row & 63;
      int bb = row >> 14;
      int sy = ((win >> 4) & 15)*8 + (tok >> 3);
      int sx = (win & 15)*8 + (tok & 7);
      int oy = (sy + 4) & 127, ox = (sx + 4) & 127;
      size_t rowb = ((size_t)((bb*128 + oy)*128 + ox)) << 8;
#pragma unroll
      for (int nj = 0; nj < 4; ++nj) {
        int ch = colg + nj*16 + q;
        out[rowb + ch] = x[rowb + ch] + acc[mi][nj][r] + pb4[nj];
      }
    }
}

// ---------------------------------------------------------------- K6 (fused path): attn + dw-add + proj + residual
__global__ __launch_bounds__(512) void k_attnproj(
    const unsigned short* __restrict__ Qb, const unsigned short* __restrict__ Kb,
    const unsigned short* __restrict__ Vt, const unsigned short* __restrict__ dwy,
    const unsigned short* __restrict__ wbp, const float* __restrict__ projb,
    const float* __restrict__ rpb, const float* __restrict__ x,
    float* __restrict__ out) {
  __shared__ unsigned short A2[16640];      // [64][260] bf16
  __shared__ unsigned short pp[8][2560];    // per-wave [64][40] P buf
  __shared__ float rpbs[1800];
  int t = threadIdx.x;
  int h = t >> 6, l = t & 63, g = l >> 4, q = l & 15;
  int win = blockIdx.x;
  int bb = win >> 8, wy = (win >> 4) & 15, wx = win & 15;
  int wy15 = (wy == 15), wx15 = (wx == 15);
  size_t base = ((size_t)(win*8 + h)) << 11;
  unsigned short* ph = pp[h];

  for (int i = t; i < 1800; i += 512) rpbs[i] = rpb[i];
  for (int i = t; i < 2048; i += 512) {
    int row = i >> 5, col = (i & 31) << 3;
    *(uint4*)&A2[row*260 + col] = *(const uint4*)(dwy + (size_t)win*16384 + i*8);
  }
  __syncthreads();

  f4v sM[4][4];
#pragma unroll
  for (int mi = 0; mi < 4; ++mi)
#pragma unroll
    for (int nj = 0; nj < 4; ++nj) sM[mi][nj] = f4v{0.f,0.f,0.f,0.f};
  {
    s8v qa[4], kb[4];
#pragma unroll
    for (int mi = 0; mi < 4; ++mi)
      qa[mi] = *(const s8v*)(Qb + (size_t)win*16384 + (mi*16 + q)*256 + h*32 + g*8);
#pragma unroll
    for (int nj = 0; nj < 4; ++nj) kb[nj] = *(const s8v*)(Kb + base + (nj*16 + q)*32 + g*8);
#pragma unroll
    for (int mi = 0; mi < 4; ++mi)
#pragma unroll
      for (int nj = 0; nj < 4; ++nj)
        sM[mi][nj] = __builtin_amdgcn_mfma_f32_16x16x32_bf16(qa[mi], kb[nj], sM[mi][nj], 0, 0, 0);
  }
  float rin[4][4];
#pragma unroll
  for (int mi = 0; mi < 4; ++mi)
#pragma unroll
    for (int r = 0; r < 4; ++r) {
      int i = mi*16 + g*4 + r;
      int iy = i >> 3, ix = i & 7;
      float sm = 0.f;
#pragma unroll
      for (int nj = 0; nj < 4; ++nj) {
        int j = nj*16 + q;
        int jy = j >> 3, jx = j & 7;
        int rel = (iy - jy + 7)*15 + (ix - jx + 7);
        int msk = (wy15 & (((iy ^ jy) >> 2) & 1)) | (wx15 & (((ix ^ jx) >> 2) & 1));
        float e = __expf(sM[mi][nj][r] + rpbs[rel*8 + h] + (msk ? -100.0f : 0.0f));
        sM[mi][nj][r] = e;
        sm += e;
      }
      sm += __shfl_xor(sm, 1);
      sm += __shfl_xor(sm, 2);
      sm += __shfl_xor(sm, 4);
      sm += __shfl_xor(sm, 8);
      rin[mi][r] = 1.0f / sm;
    }
  f4v oc[4][2];
#pragma unroll
  for (int mi = 0; mi < 4; ++mi)
#pragma unroll
    for (int nv = 0; nv < 2; ++nv) oc[mi][nv] = f4v{0.f,0.f,0.f,0.f};
  for (int half = 0; half < 2; ++half) {
#pragma unroll
    for (int mi = 0; mi < 4; ++mi)
#pragma unroll
      for (int nl = 0; nl < 2; ++nl)
#pragma unroll
        for (int r = 0; r < 4; ++r) {
          int i = mi*16 + g*4 + r;
          ph[i*40 + nl*16 + q] = f2bf(sM[mi][half*2 + nl][r] * rin[mi][r]);
        }
    s8v pa[4], vb[2];
#pragma unroll
    for (int mi = 0; mi < 4; ++mi) pa[mi] = *(const s8v*)(ph + (mi*16 + q)*40 + g*8);
#pragma unroll
    for (int nv = 0; nv < 2; ++nv)
      vb[nv] = *(const s8v*)(Vt + base + (nv*16 + q)*64 + half*32 + g*8);
#pragma unroll
    for (int mi = 0; mi < 4; ++mi)
#pragma unroll
      for (int nv = 0; nv < 2; ++nv)
        oc[mi][nv] = __builtin_amdgcn_mfma_f32_16x16x32_bf16(pa[mi], vb[nv], oc[mi][nv], 0, 0, 0);
  }
#pragma unroll
  for (int mi = 0; mi < 4; ++mi)
#pragma unroll
    for (int nv = 0; nv < 2; ++nv)
#pragma unroll
      for (int r = 0; r < 4; ++r) {
        int tok = mi*16 + g*4 + r;
        int idx = tok*260 + h*32 + nv*16 + q;
        A2[idx] = f2bf(oc[mi][nv][r] + bf2f(A2[idx]));
      }
  __syncthreads();

  f4v acc[4][2];
#pragma unroll
  for (int mi = 0; mi < 4; ++mi)
#pragma unroll
    for (int nv = 0; nv < 2; ++nv) acc[mi][nv] = f4v{0.f,0.f,0.f,0.f};
#pragma unroll 2
  for (int kc = 0; kc < 8; ++kc) {
    s8v af[4];
#pragma unroll
    for (int mi = 0; mi < 4; ++mi)
      af[mi] = *(const s8v*)&A2[(mi*16 + q)*260 + kc*32 + g*8];
    s8v bf2v[2];
#pragma unroll
    for (int nv = 0; nv < 2; ++nv)
      bf2v[nv] = *(const s8v*)(wbp + (size_t)(h*32 + nv*16 + q)*256 + kc*32 + g*8);
#pragma unroll
    for (int mi = 0; mi < 4; ++mi)
#pragma unroll
      for (int nv = 0; nv < 2; ++nv)
        acc[mi][nv] = __builtin_amdgcn_mfma_f32_16x16x32_bf16(af[mi], bf2v[nv], acc[mi][nv], 0, 0, 0);
  }
  float pb2[2];
  pb2[0] = projb[h*32 + q];
  pb2[1] = projb[h*32 + 16 + q];
#pragma unroll
  for (int mi = 0; mi < 4; ++mi)
#pragma unroll
    for (int r = 0; r < 4; ++r) {
      int tok = mi*16 + g*4 + r;
      int sy = wy*8 + (tok >> 3), sx = wx*8 + (tok & 7);
      int oy = (sy + 4) & 127, ox = (sx + 4) & 127;
      size_t rowb = ((size_t)((bb*128 + oy)*128 + ox)) << 8;
#pragma unroll
      for (int nv = 0; nv < 2; ++nv) {
        int ch = h*32 + nv*16 + q;
        out[rowb + ch] = x[rowb + ch] + acc[mi][nv][r] + pb2[nv];
      }
    }
}

extern "C" void kernel_launch(void* const* d_in, const int* in_sizes, int n_in,
                              void* d_out, int out_size, void* d_ws, size_t ws_size,
                              hipStream_t stream) {
  (void)in_sizes; (void)n_in; (void)out_size;
  const float* x     = (const float*)d_in[0];
  // d_in[1] = mask (analytic), d_in[2] = x_size (hardcoded 128)
  const float* g     = (const float*)d_in[3];
  const float* bln   = (const float*)d_in[4];
  const float* dww   = (const float*)d_in[5];
  const float* dwb_  = (const float*)d_in[6];
  const float* qkvw  = (const float*)d_in[7];
  const float* qkvb  = (const float*)d_in[8];
  const float* projw = (const float*)d_in[9];
  const float* projb = (const float*)d_in[10];
  const float* rpb   = (const float*)d_in[11];

  unsigned short* wsu = (unsigned short*)d_ws;
  unsigned short* xnw = wsu;                  // 64 MiB: xn -> Q in place
  unsigned short* dwy = wsu + 33554432;       // 64 MiB: dw (-> yio in split path)
  bool fused = ws_size >= 268959744ull;       // 256.5 MiB
  bool bw    = fused || ws_size >= 134742016ull;  // 128.5 MiB
  unsigned short *Kb, *Vt, *wb;
  if (fused) {
    Kb = wsu + 67108864;                      // ws + 128 MiB
    Vt = wsu + 100663296;                     // ws + 192 MiB
    wb = wsu + 134217728;                     // ws + 256 MiB
  } else {
    Kb = (unsigned short*)d_out;              // d_out doubles as K|Vt until k_proj
    Vt = Kb + 33554432;
    wb = wsu + 67108864;                      // ws + 128 MiB
  }
  float* outp = (float*)d_out;

  if (bw) k_wcvt<<<dim3(128), dim3(256), 0, stream>>>(qkvw, projw, wb);
  k_ln<<<dim3(32768),     dim3(256), 0, stream>>>(x, g, bln, xnw);
  k_dw<<<dim3(8, 8, 128), dim3(256), 0, stream>>>(xnw, dww, dwb_, dwy);
  if (bw) k_qkvm<true ><<<dim3(2048), dim3(256), 0, stream>>>(xnw, wb, qkvw, qkvb, Kb, Vt);
  else    k_qkvm<false><<<dim3(2048), dim3(256), 0, stream>>>(xnw, wb, qkvw, qkvb, Kb, Vt);

  if (fused) {
    k_attnproj<<<dim3(2048), dim3(512), 0, stream>>>(xnw, Kb, Vt, dwy, wb + 196608,
                                                     projb, rpb, x, outp);
  } else {
    k_attn<<<dim3(16384), dim3(64), 0, stream>>>(xnw, Kb, Vt, rpb, dwy);
    if (bw) k_proj<true ><<<dim3(2048), dim3(256), 0, stream>>>(dwy, wb + 196608, projw, projb, x, outp);
    else    k_proj<false><<<dim3(2048), dim3(256), 0, stream>>>(dwy, wb + 196608, projw, projb, x, outp);
  }
}